// Round 1
// baseline (473.655 us; speedup 1.0000x reference)
//
#include <hip/hip_runtime.h>
#include <math.h>

// Problem constants (match reference)
namespace {
constexpr int B = 2, F = 32, T = 1024, D = 1024;
constexpr int H = 512, W = 512;
constexpr int HWN = H * W;                   // 262144 elements per (b,f) mask
constexpr float BASE_BLEND = 0.1f;           // 1 - DECAY
constexpr float COS_EPS = 1e-6f;
constexpr int COV_SUB = 16;                  // blocks per (b,f) mask slice
}

// ---------------------------------------------------------------------------
// Kernel 1: partial clip+sum of each mask slice. 16 blocks per (b,f) slice so
// the 64MB read uses all CUs. float4 loads, wave shuffle reduce, tiny LDS.
// ---------------------------------------------------------------------------
__global__ __launch_bounds__(256) void cov_partial_kernel(
    const float* __restrict__ masks, float* __restrict__ partial) {
  const int s   = blockIdx.x >> 4;           // (b*F + f) slice
  const int sub = blockIdx.x & (COV_SUB - 1);
  const float4* p = reinterpret_cast<const float4*>(masks) +
                    (size_t)s * (HWN / 4) + (size_t)sub * (HWN / 4 / COV_SUB);
  float sum = 0.f;
#pragma unroll
  for (int i = 0; i < 16; ++i) {             // 16 float4 per thread
    float4 v = p[i * 256 + threadIdx.x];
    sum += fminf(fmaxf(v.x, 0.f), 1.f);
    sum += fminf(fmaxf(v.y, 0.f), 1.f);
    sum += fminf(fmaxf(v.z, 0.f), 1.f);
    sum += fminf(fmaxf(v.w, 0.f), 1.f);
  }
#pragma unroll
  for (int m = 32; m; m >>= 1) sum += __shfl_xor(sum, m, 64);
  __shared__ float sw[4];
  if ((threadIdx.x & 63) == 0) sw[threadIdx.x >> 6] = sum;
  __syncthreads();
  if (threadIdx.x == 0) partial[blockIdx.x] = sw[0] + sw[1] + sw[2] + sw[3];
}

// ---------------------------------------------------------------------------
// Kernel 2: fold 16 partials per slice into the coverage mean (64 scalars).
// ---------------------------------------------------------------------------
__global__ void cov_final_kernel(const float* __restrict__ partial,
                                 float* __restrict__ cov) {
  const int i = threadIdx.x;                 // 0..63 == b*F + f
  float s = 0.f;
#pragma unroll
  for (int j = 0; j < COV_SUB; ++j) s += partial[i * COV_SUB + j];
  cov[i] = s * (1.0f / (float)HWN);
}

// ---------------------------------------------------------------------------
// Kernel 3: the scan. One wave per (b,t) row; the D=1024 memory state lives in
// 16 registers/lane (4 x float4). Cosine reduction = 64-lane shfl_xor
// butterfly; no LDS, no barriers. Next frame's tokens are prefetched before
// the reduction so HBM latency hides under the shuffle + sigmoid chain.
// ---------------------------------------------------------------------------
#define DOT4(a, b) ((a).x * (b).x + (a).y * (b).y + (a).z * (b).z + (a).w * (b).w)
#define EMA4(m, c, bl)                 \
  do {                                 \
    (m).x += (bl) * ((c).x - (m).x);   \
    (m).y += (bl) * ((c).y - (m).y);   \
    (m).z += (bl) * ((c).z - (m).z);   \
    (m).w += (bl) * ((c).w - (m).w);   \
  } while (0)

__global__ __launch_bounds__(256) void tracker_kernel(
    const float4* __restrict__ toks, const float* __restrict__ cov,
    float4* __restrict__ out) {
  const int tid  = threadIdx.x;
  const int wv   = tid >> 6;
  const int lane = tid & 63;
  const int r    = blockIdx.x * 4 + wv;      // row index: b*T + t
  const int b    = r >> 10;                  // T = 1024
  const int t    = r & 1023;

  const size_t rowbase = ((size_t)b * F * T + (size_t)t) * (D / 4);
  const size_t fs      = (size_t)T * (D / 4);  // float4 stride between frames
  const float4* tp = toks + rowbase + lane;
  float4*       op = out  + rowbase + lane;
  const float* covp = cov + b * F;

  // f = 0: memory = tokens, copy through.
  float4 m0 = tp[0],  m1 = tp[64], m2 = tp[128], m3 = tp[192];
  op[0] = m0; op[64] = m1; op[128] = m2; op[192] = m3;

  // prefetch f = 1
  float4 c0 = tp[fs], c1 = tp[fs + 64], c2 = tp[fs + 128], c3 = tp[fs + 192];

  for (int f = 1; f < F; ++f) {
    // prefetch f+1 while we reduce/compute on f
    float4 n0, n1, n2, n3;
    if (f + 1 < F) {
      const float4* np = tp + (size_t)(f + 1) * fs;
      n0 = np[0]; n1 = np[64]; n2 = np[128]; n3 = np[192];
    }

    float dot = DOT4(c0, m0) + DOT4(c1, m1) + DOT4(c2, m2) + DOT4(c3, m3);
    float nc  = DOT4(c0, c0) + DOT4(c1, c1) + DOT4(c2, c2) + DOT4(c3, c3);
    float nm  = DOT4(m0, m0) + DOT4(m1, m1) + DOT4(m2, m2) + DOT4(m3, m3);

#pragma unroll
    for (int msk = 32; msk; msk >>= 1) {
      dot += __shfl_xor(dot, msk, 64);
      nc  += __shfl_xor(nc,  msk, 64);
      nm  += __shfl_xor(nm,  msk, 64);
    }

    const float sim = dot / (fmaxf(sqrtf(nc), COS_EPS) * fmaxf(sqrtf(nm), COS_EPS));
    float gate = 1.0f / (1.0f + expf(-sim / 0.07f));
    gate *= 0.5f + 0.5f * covp[f];
    float bl = BASE_BLEND * (0.5f + gate);
    bl = fminf(fmaxf(bl, 0.0f), 1.0f);

    EMA4(m0, c0, bl); EMA4(m1, c1, bl); EMA4(m2, c2, bl); EMA4(m3, c3, bl);

    float4* o = op + (size_t)f * fs;
    o[0] = m0; o[64] = m1; o[128] = m2; o[192] = m3;

    c0 = n0; c1 = n1; c2 = n2; c3 = n3;
  }
}

// ---------------------------------------------------------------------------
extern "C" void kernel_launch(void* const* d_in, const int* in_sizes, int n_in,
                              void* d_out, int out_size, void* d_ws, size_t ws_size,
                              hipStream_t stream) {
  const float* toks  = (const float*)d_in[0];   // [B,F,T,D] f32
  const float* masks = (const float*)d_in[1];   // [B,F,H,W] f32
  float* out = (float*)d_out;                   // [B,F,T,D] f32

  float* partial = (float*)d_ws;                // B*F*COV_SUB = 1024 floats
  float* cov     = partial + B * F * COV_SUB;   // 64 floats

  cov_partial_kernel<<<B * F * COV_SUB, 256, 0, stream>>>(masks, partial);
  cov_final_kernel<<<1, 64, 0, stream>>>(partial, cov);
  tracker_kernel<<<(B * T) / 4, 256, 0, stream>>>(
      (const float4*)toks, cov, (float4*)out);
}